// Round 4
// baseline (451.585 us; speedup 1.0000x reference)
//
#include <hip/hip_runtime.h>
#include <stdint.h>

#define S_LEN 4096
#define DM 1024
#define NH 16
#define DKH 64
#define LDQ (3 * DM)

typedef __attribute__((ext_vector_type(8))) __bf16 bf16x8;
typedef __attribute__((ext_vector_type(8))) short s16x8;
typedef __attribute__((ext_vector_type(4))) float f32x4;

__device__ inline unsigned short f2bf(float f) {
  unsigned int u = __builtin_bit_cast(unsigned int, f);
  u += 0x7fff + ((u >> 16) & 1);   // RNE
  return (unsigned short)(u >> 16);
}
__device__ inline float bf2f(unsigned short u) {
  return __builtin_bit_cast(float, (unsigned int)u << 16);
}

__device__ inline f32x4 mfma16(s16x8 a, s16x8 b, f32x4 c) {
  return __builtin_amdgcn_mfma_f32_16x16x32_bf16(
      __builtin_bit_cast(bf16x8, a), __builtin_bit_cast(bf16x8, b), c, 0, 0, 0);
}

__device__ inline void gld_lds16(const unsigned short* g, unsigned short* l) {
  __builtin_amdgcn_global_load_lds(
      (const __attribute__((address_space(1))) unsigned int*)g,
      (__attribute__((address_space(3))) unsigned int*)l, 16, 0, 0);
}

__global__ void convert_f32_bf16(const float* __restrict__ in,
                                 unsigned short* __restrict__ out, int n4) {
  int i = blockIdx.x * blockDim.x + threadIdx.x;
  if (i >= n4) return;
  float4 v = reinterpret_cast<const float4*>(in)[i];
  ushort4 o;
  o.x = f2bf(v.x); o.y = f2bf(v.y); o.z = f2bf(v.z); o.w = f2bf(v.w);
  reinterpret_cast<ushort4*>(out)[i] = o;
}

__device__ inline void storeC(unsigned short* C, size_t i, float v) { C[i] = f2bf(v); }
__device__ inline void storeC(float* C, size_t i, float v) { C[i] = v; }

// C[m][n] = sum_k A[m][k] * B[n][k]
template <typename OutT>
__global__ __launch_bounds__(256) void gemm_bt(const unsigned short* __restrict__ A,
                                               const unsigned short* __restrict__ B,
                                               OutT* __restrict__ C, int M, int N, int K) {
  __shared__ __align__(16) unsigned short lds_a[128 * 64];
  __shared__ __align__(16) unsigned short lds_b[128 * 64];
  const int tid = threadIdx.x;
  const int lane = tid & 63;
  const int w = tid >> 6;
  const int wr = w >> 1, wc = w & 1;
  const int l15 = lane & 15, lhi = lane >> 4;
  const int bm0 = blockIdx.x * 128, bn0 = blockIdx.y * 128;
  const int srow = lane >> 3;
  const int scol = (lane & 7) * 8;

  f32x4 acc[4][4] = {};

  for (int k0 = 0; k0 < K; k0 += 64) {
    __syncthreads();
#pragma unroll
    for (int i = 0; i < 4; ++i) {
      const int base = i * 2048 + w * 512;
      const int row = i * 32 + w * 8 + srow;
      gld_lds16(A + (size_t)(bm0 + row) * K + k0 + scol, lds_a + base);
      gld_lds16(B + (size_t)(bn0 + row) * K + k0 + scol, lds_b + base);
    }
    __syncthreads();
#pragma unroll
    for (int kk = 0; kk < 2; ++kk) {
      s16x8 af[4], bfr[4];
#pragma unroll
      for (int mi = 0; mi < 4; ++mi)
        af[mi] = *(const s16x8*)&lds_a[(wr * 64 + mi * 16 + l15) * 64 + kk * 32 + lhi * 8];
#pragma unroll
      for (int ni = 0; ni < 4; ++ni)
        bfr[ni] = *(const s16x8*)&lds_b[(wc * 64 + ni * 16 + l15) * 64 + kk * 32 + lhi * 8];
#pragma unroll
      for (int mi = 0; mi < 4; ++mi)
#pragma unroll
        for (int ni = 0; ni < 4; ++ni)
          acc[mi][ni] = mfma16(af[mi], bfr[ni], acc[mi][ni]);
    }
  }
#pragma unroll
  for (int mi = 0; mi < 4; ++mi)
#pragma unroll
    for (int ni = 0; ni < 4; ++ni)
#pragma unroll
      for (int r = 0; r < 4; ++r) {
        int row = bm0 + wr * 64 + mi * 16 + lhi * 4 + r;
        int col = bn0 + wc * 64 + ni * 16 + l15;
        storeC(C, (size_t)row * N + col, acc[mi][ni][r]);
      }
}

// V^T per head: vTg[(h*DKH + dk)*S + s] = QKV[s][2*DM + h*DKH + dk]
__global__ __launch_bounds__(256) void transpose_v(const unsigned short* __restrict__ QKV,
                                                   unsigned short* __restrict__ vTg) {
  const int s0 = blockIdx.x * 64;
  const int h = blockIdx.y;
  __shared__ __align__(16) unsigned short t[64][72];
  const int r = threadIdx.x >> 2;          // s-local row 0..63
  const int c = (threadIdx.x & 3) * 16;    // dk chunk
  const unsigned short* src = QKV + (size_t)(s0 + r) * LDQ + 2 * DM + h * DKH + c;
#pragma unroll
  for (int j = 0; j < 16; j += 4)
    *(ushort4*)&t[r][c + j] = *(const ushort4*)(src + j);
  __syncthreads();
  const int d = threadIdx.x >> 2;          // dk row 0..63
  const int sc = (threadIdx.x & 3) * 16;   // s chunk
  unsigned short* dst = vTg + (size_t)(h * DKH + d) * S_LEN + s0 + sc;
#pragma unroll
  for (int j = 0; j < 16; j += 4) {
    ushort4 v;
    v.x = t[sc + j + 0][d]; v.y = t[sc + j + 1][d];
    v.z = t[sc + j + 2][d]; v.w = t[sc + j + 3][d];
    *(ushort4*)(dst + j) = v;
  }
}

// one k-tile of flash attention for one wave (16 q-rows)
template <bool MASK>
__device__ inline void attn_tile(const unsigned short* __restrict__ Kp,
                                 const unsigned short* __restrict__ vTg,
                                 unsigned short (*pb)[72], const s16x8 qf[2],
                                 int kb, int h, int qrow0, int l15, int lhi,
                                 f32x4 o[4], float m_r[4], float l_r[4]) {
  f32x4 sf[4];
#pragma unroll
  for (int st = 0; st < 4; ++st) {
    f32x4 acc = {};
#pragma unroll
    for (int kk = 0; kk < 2; ++kk) {
      s16x8 kf = *(const s16x8*)&Kp[(size_t)(kb + st * 16 + l15) * LDQ + h * DKH + kk * 32 + lhi * 8];
      acc = mfma16(qf[kk], kf, acc);
    }
    sf[st] = acc;
  }
  if (MASK) {
#pragma unroll
    for (int st = 0; st < 4; ++st) {
      const int key = kb + st * 16 + l15;
#pragma unroll
      for (int r = 0; r < 4; ++r) {
        const int qrow = qrow0 + lhi * 4 + r;
        if (key > qrow) sf[st][r] = -1e30f;
      }
    }
  }
  float alpha[4];
#pragma unroll
  for (int r = 0; r < 4; ++r) {
    float mx = fmaxf(fmaxf(sf[0][r], sf[1][r]), fmaxf(sf[2][r], sf[3][r]));
#pragma unroll
    for (int d = 1; d < 16; d <<= 1) mx = fmaxf(mx, __shfl_xor(mx, d));
    const float mn = fmaxf(m_r[r], mx);
    alpha[r] = __expf(m_r[r] - mn);
    m_r[r] = mn;
    float rs = 0.f;
#pragma unroll
    for (int st = 0; st < 4; ++st) {
      const float p = __expf(sf[st][r] - mn);
      sf[st][r] = p;
      rs += p;
    }
#pragma unroll
    for (int d = 1; d < 16; d <<= 1) rs += __shfl_xor(rs, d);
    l_r[r] = l_r[r] * alpha[r] + rs;
  }
  // P -> wave-private LDS (intra-wave: DS pipe is in-order per wave, no barrier)
#pragma unroll
  for (int st = 0; st < 4; ++st)
#pragma unroll
    for (int r = 0; r < 4; ++r)
      pb[lhi * 4 + r][st * 16 + l15] = f2bf(sf[st][r]);
#pragma unroll
  for (int n = 0; n < 4; ++n)
#pragma unroll
    for (int r = 0; r < 4; ++r) o[n][r] *= alpha[r];
#pragma unroll
  for (int kk = 0; kk < 2; ++kk) {
    s16x8 pa = *(const s16x8*)&pb[l15][kk * 32 + lhi * 8];
#pragma unroll
    for (int n = 0; n < 4; ++n) {
      s16x8 vb = *(const s16x8*)&vTg[(size_t)(h * DKH + n * 16 + l15) * S_LEN + kb + kk * 32 + lhi * 8];
      o[n] = mfma16(pa, vb, o[n]);
    }
  }
}

// grid (32, NH): block = (q-tile pair {p, 63-p}, head). 4 independent waves,
// wave w owns q-rows [qt*64 + 16w, +16). No __syncthreads in this kernel.
__global__ __launch_bounds__(256) void attn_causal2(const unsigned short* __restrict__ QKV,
                                                    const unsigned short* __restrict__ vTg,
                                                    unsigned short* __restrict__ CTX) {
  const int flat = blockIdx.x + 32 * blockIdx.y;
  const int swz = (flat & 7) * 64 + (flat >> 3);   // 512 % 8 == 0: bijective XCD swizzle
  const int pr = swz & 31;
  const int h = swz >> 5;
  const int tid = threadIdx.x;
  const int lane = tid & 63, w = tid >> 6;
  const int l15 = lane & 15, lhi = lane >> 4;
  __shared__ __align__(16) unsigned short pbuf[4][16][72];
  unsigned short (*pb)[72] = pbuf[w];

  const unsigned short* Qp = QKV;
  const unsigned short* Kp = QKV + DM;

#pragma unroll 1
  for (int half = 0; half < 2; ++half) {
    const int qt = half ? (63 - pr) : pr;
    const int qrow0 = qt * 64 + w * 16;
    s16x8 qf[2];
#pragma unroll
    for (int kk = 0; kk < 2; ++kk) {
      s16x8 q = *(const s16x8*)&Qp[(size_t)(qrow0 + l15) * LDQ + h * DKH + kk * 32 + lhi * 8];
#pragma unroll
      for (int e = 0; e < 8; ++e)
        q[e] = (short)f2bf(bf2f((unsigned short)q[e]) * 0.125f);  // fold 1/sqrt(64), exact
      qf[kk] = q;
    }
    f32x4 o[4] = {};
    float m_r[4], l_r[4];
#pragma unroll
    for (int r = 0; r < 4; ++r) { m_r[r] = -1e30f; l_r[r] = 0.f; }

#pragma unroll 1
    for (int kbi = 0; kbi < qt; ++kbi)
      attn_tile<false>(Kp, vTg, pb, qf, kbi * 64, h, qrow0, l15, lhi, o, m_r, l_r);
    attn_tile<true>(Kp, vTg, pb, qf, qt * 64, h, qrow0, l15, lhi, o, m_r, l_r);

#pragma unroll
    for (int n = 0; n < 4; ++n)
#pragma unroll
      for (int r = 0; r < 4; ++r) {
        const int qrow = qrow0 + lhi * 4 + r;
        CTX[(size_t)qrow * DM + h * DKH + n * 16 + l15] = f2bf(o[n][r] / l_r[r]);
      }
  }
}

extern "C" void kernel_launch(void* const* d_in, const int* in_sizes, int n_in,
                              void* d_out, int out_size, void* d_ws, size_t ws_size,
                              hipStream_t stream) {
  const float* x  = (const float*)d_in[0];
  const float* Wq = (const float*)d_in[1];
  const float* Wk = (const float*)d_in[2];
  const float* Wv = (const float*)d_in[3];
  const float* Wo = (const float*)d_in[4];
  float* out = (float*)d_out;
  char* ws = (char*)d_ws;

  unsigned short* x_bf  = (unsigned short*)(ws + 0);
  unsigned short* wqkv  = (unsigned short*)(ws + (size_t)8 * 1024 * 1024);
  unsigned short* wo_bf = (unsigned short*)(ws + (size_t)14 * 1024 * 1024);
  unsigned short* qkv   = (unsigned short*)(ws + (size_t)16 * 1024 * 1024);
  unsigned short* ctx   = (unsigned short*)(ws + (size_t)40 * 1024 * 1024);
  unsigned short* vTg   = (unsigned short*)(ws + (size_t)48 * 1024 * 1024);

  const int n4x = S_LEN * DM / 4;
  convert_f32_bf16<<<(n4x + 255) / 256, 256, 0, stream>>>(x, x_bf, n4x);
  const int w4 = DM * DM / 4;
  convert_f32_bf16<<<(w4 + 255) / 256, 256, 0, stream>>>(Wq, wqkv, w4);
  convert_f32_bf16<<<(w4 + 255) / 256, 256, 0, stream>>>(Wk, wqkv + DM * DM, w4);
  convert_f32_bf16<<<(w4 + 255) / 256, 256, 0, stream>>>(Wv, wqkv + 2 * DM * DM, w4);
  convert_f32_bf16<<<(w4 + 255) / 256, 256, 0, stream>>>(Wo, wo_bf, w4);

  dim3 g1(S_LEN / 128, (3 * DM) / 128);
  gemm_bt<unsigned short><<<g1, 256, 0, stream>>>(x_bf, wqkv, qkv, S_LEN, 3 * DM, DM);

  dim3 gt(S_LEN / 64, NH);
  transpose_v<<<gt, 256, 0, stream>>>(qkv, vTg);

  dim3 g2(32, NH);
  attn_causal2<<<g2, 256, 0, stream>>>(qkv, vTg, ctx);

  dim3 g3(S_LEN / 128, DM / 128);
  gemm_bt<float><<<g3, 256, 0, stream>>>(ctx, wo_bf, out, S_LEN, DM, DM);
}

// Round 6
// 297.718 us; speedup vs baseline: 1.5168x; 1.5168x over previous
//
#include <hip/hip_runtime.h>
#include <stdint.h>

#define S_LEN 4096
#define DM 1024
#define NH 16
#define DKH 64
#define LDQ (3 * DM)

typedef __attribute__((ext_vector_type(8))) __bf16 bf16x8;
typedef __attribute__((ext_vector_type(8))) short s16x8;
typedef __attribute__((ext_vector_type(4))) float f32x4;

__device__ inline unsigned short f2bf(float f) {
  unsigned int u = __builtin_bit_cast(unsigned int, f);
  u += 0x7fff + ((u >> 16) & 1);   // RNE
  return (unsigned short)(u >> 16);
}
__device__ inline float bf2f(unsigned short u) {
  return __builtin_bit_cast(float, (unsigned int)u << 16);
}

__device__ inline f32x4 mfma16(s16x8 a, s16x8 b, f32x4 c) {
  return __builtin_amdgcn_mfma_f32_16x16x32_bf16(
      __builtin_bit_cast(bf16x8, a), __builtin_bit_cast(bf16x8, b), c, 0, 0, 0);
}

__device__ inline void gld_lds16(const unsigned short* g, unsigned short* l) {
  __builtin_amdgcn_global_load_lds(
      (const __attribute__((address_space(1))) unsigned int*)g,
      (__attribute__((address_space(3))) unsigned int*)l, 16, 0, 0);
}

__global__ void convert_f32_bf16(const float* __restrict__ in,
                                 unsigned short* __restrict__ out, int n4) {
  int i = blockIdx.x * blockDim.x + threadIdx.x;
  if (i >= n4) return;
  float4 v = reinterpret_cast<const float4*>(in)[i];
  ushort4 o;
  o.x = f2bf(v.x); o.y = f2bf(v.y); o.z = f2bf(v.z); o.w = f2bf(v.w);
  reinterpret_cast<ushort4*>(out)[i] = o;
}

__device__ inline void storeC(unsigned short* C, size_t i, float v) { C[i] = f2bf(v); }
__device__ inline void storeC(float* C, size_t i, float v) { C[i] = v; }

// C[m][n] = sum_k A[m][k] * B[n][k]
template <typename OutT>
__global__ __launch_bounds__(256) void gemm_bt(const unsigned short* __restrict__ A,
                                               const unsigned short* __restrict__ B,
                                               OutT* __restrict__ C, int M, int N, int K) {
  __shared__ __align__(16) unsigned short lds_a[128 * 64];
  __shared__ __align__(16) unsigned short lds_b[128 * 64];
  const int tid = threadIdx.x;
  const int lane = tid & 63;
  const int w = tid >> 6;
  const int wr = w >> 1, wc = w & 1;
  const int l15 = lane & 15, lhi = lane >> 4;
  const int bm0 = blockIdx.x * 128, bn0 = blockIdx.y * 128;
  const int srow = lane >> 3;
  const int scol = (lane & 7) * 8;

  f32x4 acc[4][4] = {};

  for (int k0 = 0; k0 < K; k0 += 64) {
    __syncthreads();
#pragma unroll
    for (int i = 0; i < 4; ++i) {
      const int base = i * 2048 + w * 512;
      const int row = i * 32 + w * 8 + srow;
      gld_lds16(A + (size_t)(bm0 + row) * K + k0 + scol, lds_a + base);
      gld_lds16(B + (size_t)(bn0 + row) * K + k0 + scol, lds_b + base);
    }
    __syncthreads();
#pragma unroll
    for (int kk = 0; kk < 2; ++kk) {
      s16x8 af[4], bfr[4];
#pragma unroll
      for (int mi = 0; mi < 4; ++mi)
        af[mi] = *(const s16x8*)&lds_a[(wr * 64 + mi * 16 + l15) * 64 + kk * 32 + lhi * 8];
#pragma unroll
      for (int ni = 0; ni < 4; ++ni)
        bfr[ni] = *(const s16x8*)&lds_b[(wc * 64 + ni * 16 + l15) * 64 + kk * 32 + lhi * 8];
#pragma unroll
      for (int mi = 0; mi < 4; ++mi)
#pragma unroll
        for (int ni = 0; ni < 4; ++ni)
          acc[mi][ni] = mfma16(af[mi], bfr[ni], acc[mi][ni]);
    }
  }
#pragma unroll
  for (int mi = 0; mi < 4; ++mi)
#pragma unroll
    for (int ni = 0; ni < 4; ++ni)
#pragma unroll
      for (int r = 0; r < 4; ++r) {
        int row = bm0 + wr * 64 + mi * 16 + lhi * 4 + r;
        int col = bn0 + wc * 64 + ni * 16 + l15;
        storeC(C, (size_t)row * N + col, acc[mi][ni][r]);
      }
}

// V^T per head: vTg[(h*DKH + dk)*S + s] = QKV[s][2*DM + h*DKH + dk]
__global__ __launch_bounds__(256) void transpose_v(const unsigned short* __restrict__ QKV,
                                                   unsigned short* __restrict__ vTg) {
  const int s0 = blockIdx.x * 64;
  const int h = blockIdx.y;
  __shared__ __align__(16) unsigned short t[64][72];
  const int r = threadIdx.x >> 2;
  const int c = (threadIdx.x & 3) * 16;
  const unsigned short* src = QKV + (size_t)(s0 + r) * LDQ + 2 * DM + h * DKH + c;
#pragma unroll
  for (int j = 0; j < 16; j += 4)
    *(ushort4*)&t[r][c + j] = *(const ushort4*)(src + j);
  __syncthreads();
  const int d = threadIdx.x >> 2;
  const int sc = (threadIdx.x & 3) * 16;
  unsigned short* dst = vTg + (size_t)(h * DKH + d) * S_LEN + s0 + sc;
#pragma unroll
  for (int j = 0; j < 16; j += 4) {
    ushort4 v;
    v.x = t[sc + j + 0][d]; v.y = t[sc + j + 1][d];
    v.z = t[sc + j + 2][d]; v.w = t[sc + j + 3][d];
    *(ushort4*)(dst + j) = v;
  }
}

// Cooperative async staging of one 64x64 K-tile and V^T-tile into LDS.
// LDS layout [row][64] linear; data is placed so that a read at
// col' = col ^ ((row&7)*8) returns the true (row, col): the SOURCE column is
// pre-swizzled (global_load_lds writes linearly; rule: swizzle both sides).
__device__ inline void stage_kv(const unsigned short* __restrict__ Kp,
                                const unsigned short* __restrict__ vTg,
                                unsigned short* lk, unsigned short* lv,
                                int kb, int h, int tid) {
  const int w = tid >> 6, l = tid & 63;
  const int sub = l >> 3;                       // 0..7
  const int src_col = 8 * ((l & 7) ^ sub);      // pre-swizzled source column
#pragma unroll
  for (int i = 0; i < 2; ++i) {
    const int row = i * 32 + w * 8 + sub;
    gld_lds16(Kp + (size_t)(kb + row) * LDQ + h * DKH + src_col,
              lk + (i * 32 + w * 8) * 64);
    gld_lds16(vTg + (size_t)(h * DKH + row) * S_LEN + kb + src_col,
              lv + (i * 32 + w * 8) * 64);
  }
}

// one k-tile of flash attention for one wave (16 q-rows), operands from LDS
template <bool MASK>
__device__ inline void attn_tile_lds(const unsigned short* __restrict__ lk,
                                     const unsigned short* __restrict__ lv,
                                     unsigned short (*pb)[72], const s16x8 qf[2],
                                     int kb, int qrow0, int l15, int lhi,
                                     f32x4 o[4], float m_r[4], float l_r[4]) {
  const int sw = (l15 & 7) * 8;   // XOR swizzle for this lane's row
  f32x4 sf[4];
#pragma unroll
  for (int st = 0; st < 4; ++st) {
    f32x4 acc = {};
#pragma unroll
    for (int kk = 0; kk < 2; ++kk) {
      s16x8 kf = *(const s16x8*)&lk[(st * 16 + l15) * 64 + ((kk * 32 + lhi * 8) ^ sw)];
      acc = mfma16(qf[kk], kf, acc);
    }
    sf[st] = acc;
  }
  if (MASK) {
#pragma unroll
    for (int st = 0; st < 4; ++st) {
      const int key = kb + st * 16 + l15;
#pragma unroll
      for (int r = 0; r < 4; ++r) {
        const int qrow = qrow0 + lhi * 4 + r;
        if (key > qrow) sf[st][r] = -1e30f;
      }
    }
  }
  float alpha[4];
#pragma unroll
  for (int r = 0; r < 4; ++r) {
    float mx = fmaxf(fmaxf(sf[0][r], sf[1][r]), fmaxf(sf[2][r], sf[3][r]));
#pragma unroll
    for (int d = 1; d < 16; d <<= 1) mx = fmaxf(mx, __shfl_xor(mx, d));
    const float mn = fmaxf(m_r[r], mx);
    alpha[r] = __expf(m_r[r] - mn);
    m_r[r] = mn;
    float rs = 0.f;
#pragma unroll
    for (int st = 0; st < 4; ++st) {
      const float p = __expf(sf[st][r] - mn);
      sf[st][r] = p;
      rs += p;
    }
#pragma unroll
    for (int d = 1; d < 16; d <<= 1) rs += __shfl_xor(rs, d);
    l_r[r] = l_r[r] * alpha[r] + rs;
  }
  // P -> wave-private LDS (intra-wave ds write->read, no barrier needed)
#pragma unroll
  for (int st = 0; st < 4; ++st)
#pragma unroll
    for (int r = 0; r < 4; ++r)
      pb[lhi * 4 + r][st * 16 + l15] = f2bf(sf[st][r]);
#pragma unroll
  for (int n = 0; n < 4; ++n)
#pragma unroll
    for (int r = 0; r < 4; ++r) o[n][r] *= alpha[r];
#pragma unroll
  for (int kk = 0; kk < 2; ++kk) {
    s16x8 pa = *(const s16x8*)&pb[l15][kk * 32 + lhi * 8];
#pragma unroll
    for (int n = 0; n < 4; ++n) {
      s16x8 vb = *(const s16x8*)&lv[(n * 16 + l15) * 64 + ((kk * 32 + lhi * 8) ^ sw)];
      o[n] = mfma16(pa, vb, o[n]);
    }
  }
}

// grid (32, NH): block = (q-tile pair {p, 63-p}, head). 4 waves share each
// K/V tile via double-buffered async LDS staging; one barrier per k-tile.
__global__ __launch_bounds__(256) void attn_causal3(const unsigned short* __restrict__ QKV,
                                                    const unsigned short* __restrict__ vTg,
                                                    unsigned short* __restrict__ CTX) {
  const int flat = blockIdx.x + 32 * blockIdx.y;
  const int swz = (flat & 7) * 64 + (flat >> 3);   // bijective XCD swizzle (512 % 8 == 0)
  const int pr = swz & 31;
  const int h = swz >> 5;
  const int tid = threadIdx.x;
  const int lane = tid & 63, w = tid >> 6;
  const int l15 = lane & 15, lhi = lane >> 4;

  __shared__ __align__(16) unsigned short lk[2][64 * 64];
  __shared__ __align__(16) unsigned short lv[2][64 * 64];
  __shared__ __align__(16) unsigned short pbuf[4][16][72];
  unsigned short (*pb)[72] = pbuf[w];

  const unsigned short* Qp = QKV;
  const unsigned short* Kp = QKV + DM;

#pragma unroll 1
  for (int half = 0; half < 2; ++half) {
    const int qt = half ? (63 - pr) : pr;
    const int qrow0 = qt * 64 + w * 16;
    s16x8 qf[2];
#pragma unroll
    for (int kk = 0; kk < 2; ++kk) {
      s16x8 q = *(const s16x8*)&Qp[(size_t)(qrow0 + l15) * LDQ + h * DKH + kk * 32 + lhi * 8];
#pragma unroll
      for (int e = 0; e < 8; ++e)
        q[e] = (short)f2bf(bf2f((unsigned short)q[e]) * 0.125f);  // fold 1/sqrt(64), exact
      qf[kk] = q;
    }
    f32x4 o[4] = {};
    float m_r[4], l_r[4];
#pragma unroll
    for (int r = 0; r < 4; ++r) { m_r[r] = -1e30f; l_r[r] = 0.f; }

    __syncthreads();               // protect buf0 from previous half's readers
    stage_kv(Kp, vTg, lk[0], lv[0], 0, h, tid);
    int cur = 0;
#pragma unroll 1
    for (int kbi = 0; kbi <= qt; ++kbi) {
      __syncthreads();             // staged buf[cur] ready (vmcnt drained at barrier)
      if (kbi < qt)
        stage_kv(Kp, vTg, lk[cur ^ 1], lv[cur ^ 1], (kbi + 1) * 64, h, tid);
      if (kbi < qt)
        attn_tile_lds<false>(lk[cur], lv[cur], pb, qf, kbi * 64, qrow0, l15, lhi, o, m_r, l_r);
      else
        attn_tile_lds<true>(lk[cur], lv[cur], pb, qf, kbi * 64, qrow0, l15, lhi, o, m_r, l_r);
      cur ^= 1;
    }

#pragma unroll
    for (int n = 0; n < 4; ++n)
#pragma unroll
      for (int r = 0; r < 4; ++r) {
        const int qrow = qrow0 + lhi * 4 + r;
        CTX[(size_t)qrow * DM + h * DKH + n * 16 + l15] = f2bf(o[n][r] / l_r[r]);
      }
  }
}

extern "C" void kernel_launch(void* const* d_in, const int* in_sizes, int n_in,
                              void* d_out, int out_size, void* d_ws, size_t ws_size,
                              hipStream_t stream) {
  const float* x  = (const float*)d_in[0];
  const float* Wq = (const float*)d_in[1];
  const float* Wk = (const float*)d_in[2];
  const float* Wv = (const float*)d_in[3];
  const float* Wo = (const float*)d_in[4];
  float* out = (float*)d_out;
  char* ws = (char*)d_ws;

  unsigned short* x_bf  = (unsigned short*)(ws + 0);
  unsigned short* wqkv  = (unsigned short*)(ws + (size_t)8 * 1024 * 1024);
  unsigned short* wo_bf = (unsigned short*)(ws + (size_t)14 * 1024 * 1024);
  unsigned short* qkv   = (unsigned short*)(ws + (size_t)16 * 1024 * 1024);
  unsigned short* ctx   = (unsigned short*)(ws + (size_t)40 * 1024 * 1024);
  unsigned short* vTg   = (unsigned short*)(ws + (size_t)48 * 1024 * 1024);

  const int n4x = S_LEN * DM / 4;
  convert_f32_bf16<<<(n4x + 255) / 256, 256, 0, stream>>>(x, x_bf, n4x);
  const int w4 = DM * DM / 4;
  convert_f32_bf16<<<(w4 + 255) / 256, 256, 0, stream>>>(Wq, wqkv, w4);
  convert_f32_bf16<<<(w4 + 255) / 256, 256, 0, stream>>>(Wk, wqkv + DM * DM, w4);
  convert_f32_bf16<<<(w4 + 255) / 256, 256, 0, stream>>>(Wv, wqkv + 2 * DM * DM, w4);
  convert_f32_bf16<<<(w4 + 255) / 256, 256, 0, stream>>>(Wo, wo_bf, w4);

  dim3 g1(S_LEN / 128, (3 * DM) / 128);
  gemm_bt<unsigned short><<<g1, 256, 0, stream>>>(x_bf, wqkv, qkv, S_LEN, 3 * DM, DM);

  dim3 gt(S_LEN / 64, NH);
  transpose_v<<<gt, 256, 0, stream>>>(qkv, vTg);

  dim3 g2(32, NH);
  attn_causal3<<<g2, 256, 0, stream>>>(qkv, vTg, ctx);

  dim3 g3(S_LEN / 128, DM / 128);
  gemm_bt<float><<<g3, 256, 0, stream>>>(ctx, wo_bf, out, S_LEN, DM, DM);
}